// Round 3
// baseline (439.972 us; speedup 1.0000x reference)
//
#include <hip/hip_runtime.h>
#include <math.h>

// Problem constants (from reference): D=256, DIN=512, F=16
#define DD 256
#define REPS 8   // replicated accumulators to reduce atomic same-address contention

// Workspace layout (float offsets) for the small stats region
#define OFF_SUMREP 0        // 2 inputs * REPS * 256 = 4096
#define OFF_H1P    4096     // 2 * 256 = 512   (pre-tanh partial sums, atomic target)
#define OFF_S1REP  4608     // 4096
#define OFF_H2P    8704     // 512
#define OFF_OREP   9216     // 4096
#define OFF_WTREP  13824    // REPS * 16 = 128
#define WS_FLOATS  13952

typedef float    f32x4 __attribute__((ext_vector_type(4)));
typedef float    f32x8 __attribute__((ext_vector_type(8)));

__device__ __forceinline__ float sigmoidf_(float x) { return 1.0f / (1.0f + __expf(-x)); }

__device__ __forceinline__ float dot8(f32x8 a, f32x8 b) {
    f32x8 m = a * b;
    return ((m[0] + m[4]) + (m[1] + m[5])) + ((m[2] + m[6]) + (m[3] + m[7]));
}

__global__ void k_zero(float* __restrict__ ws) {
    int i = blockIdx.x * 256 + threadIdx.x;
    if (i < WS_FLOATS) ws[i] = 0.0f;
}

// f32x4 block reduce (4 waves) + replicated atomic finish (for k_colsum).
__device__ __forceinline__ void block_reduce_atomic4(f32x4 acc, int t, float* dst_base) {
    __shared__ f32x4 lds[256];
    lds[t] = acc;
    __syncthreads();
    if (t < 64) {
        f32x4 s = lds[t] + lds[t + 64] + lds[t + 128] + lds[t + 192];
        float* dst = dst_base + t * 4;
        atomicAdd(dst + 0, s.x); atomicAdd(dst + 1, s.y);
        atomicAdd(dst + 2, s.z); atomicAdd(dst + 3, s.w);
    }
}

// f32x8 block reduce (8 half-wave slots) + replicated atomic finish (att kernels).
__device__ __forceinline__ void block_reduce_atomic8(f32x8 acc, int t, float* dst_base) {
    __shared__ f32x8 lds8[256];
    lds8[t] = acc;
    __syncthreads();
    const float* lf = (const float*)lds8;
    float s = 0.f;
#pragma unroll
    for (int slot = 0; slot < 8; slot++) s += lf[slot * 256 + t];   // conflict-free
    atomicAdd(dst_base + t, s);
}

// Pass A: PURE-READ column sums (no fp16 mirror anymore -- R2 showed the
// read+write mix pinned at ~2 TB/s regardless of geometry/occupancy/ILP;
// this isolates the read stream). One kernel per input for rocprof
// visibility. Flat element-space grid-stride, copy-ubench-like: stride is
// a multiple of 64 f32x4 so each thread's column (t&63) is fixed and the
// existing block reduction applies unchanged.
__global__ void k_colsum(const f32x4* __restrict__ x, int N, int inp,
                         float* __restrict__ ws) {
    int t = threadIdx.x;
    const size_t STR = 1024 * 256;         // grid stride in f32x4 elems (== 0 mod 64)
    size_t total = (size_t)N * 64;
    size_t i = (size_t)blockIdx.x * 256 + t;
    f32x4 a0 = {0.f,0.f,0.f,0.f}, a1 = a0, a2 = a0, a3 = a0;
    for (; i + 3 * STR < total; i += 4 * STR) {
        a0 += x[i];
        a1 += x[i + STR];
        a2 += x[i + 2 * STR];
        a3 += x[i + 3 * STR];
    }
    for (; i < total; i += STR) a0 += x[i];
    f32x4 acc = (a0 + a1) + (a2 + a3);
    block_reduce_atomic4(acc, t,
        ws + OFF_SUMREP + inp * (REPS * 256) + (blockIdx.x & (REPS - 1)) * 256);
}

// hP[inp] += partial of (colsum/N) @ W0 over a 16-row slice of W0.
__global__ void k_hpart(const float* __restrict__ W0, float* __restrict__ ws,
                        int srcOff, int dstOff, int N1, int N2) {
    int inp = blockIdx.x >> 4, g = blockIdx.x & 15;
    int t = threadIdx.x;
    __shared__ float temp[16];
    if (t < 16) {
        const float* src = ws + srcOff + inp * (REPS * 256) + g * 16 + t;
        float s = 0.f;
#pragma unroll
        for (int r = 0; r < REPS; r++) s += src[r * 256];
        temp[t] = s * (1.0f / (float)(inp ? N2 : N1));
    }
    __syncthreads();
    float p = 0.f;
#pragma unroll
    for (int j = 0; j < 16; j++) p += temp[j] * W0[(g * 16 + j) * 256 + t];
    atomicAdd(ws + dstOff + inp * 256 + t, p);
}

// Pass B: s1 = sum_i sigmoid(x_i . h1) * x_i.  Reads fp32 x directly
// (L3-resident after pass A: x1+x2 = 225 MB < 256 MB, no mirror pollution).
// R0 geometry (best total so far): 2 rows/wave/step, stride 4096 rows.
__global__ void k_att1(const f32x8* __restrict__ b1, const f32x8* __restrict__ b2,
                       int N1, int N2, float* __restrict__ ws) {
    int b = blockIdx.x, t = threadIdx.x;
    int inp = (b < 1024) ? 0 : 1;
    int bl = inp ? (b - 1024) : b;
    const f32x8* x = inp ? b2 : b1;
    int N = inp ? N2 : N1;
    int lane = t & 63, w = t >> 6;
    int half = lane >> 5, l32 = lane & 31;
    f32x8 h1;
#pragma unroll
    for (int j = 0; j < 8; j++) h1[j] = tanhf(ws[OFF_H1P + inp * 256 + l32 * 8 + j]);
    f32x8 acc = {0.f, 0.f, 0.f, 0.f, 0.f, 0.f, 0.f, 0.f};
    int wid = bl * 4 + w;          // [0,4096)
    int base = wid * 2;
    for (; base + 1 < N; base += 8192) {
        int row = base + half;
        f32x8 v = x[(size_t)row * 32 + l32];
        float d = dot8(v, h1);
#pragma unroll
        for (int off = 16; off; off >>= 1) d += __shfl_xor(d, off, 64);  // 32-lane half
        acc += sigmoidf_(d) * v;
    }
    if (base < N && half == 0) {           // odd-N tail (dead for even N)
        f32x8 v = x[(size_t)base * 32 + l32];
        float d = dot8(v, h1);
#pragma unroll
        for (int off = 16; off; off >>= 1) d += __shfl_xor(d, off, 64);
        acc += sigmoidf_(d) * v;
    }
    block_reduce_atomic8(acc, t, ws + OFF_S1REP + inp * (REPS * 256) + (bl & (REPS - 1)) * 256);
}

// Pass C: o = sum_i att1_i*att2_i*x_i, att2_i = sigmoid(att1_i * (x_i . h2)).
__global__ void k_att2(const f32x8* __restrict__ b1, const f32x8* __restrict__ b2,
                       int N1, int N2, float* __restrict__ ws) {
    int b = blockIdx.x, t = threadIdx.x;
    int inp = (b < 1024) ? 0 : 1;
    int bl = inp ? (b - 1024) : b;
    const f32x8* x = inp ? b2 : b1;
    int N = inp ? N2 : N1;
    int lane = t & 63, w = t >> 6;
    int half = lane >> 5, l32 = lane & 31;
    f32x8 h1, h2;
#pragma unroll
    for (int j = 0; j < 8; j++) {
        h1[j] = tanhf(ws[OFF_H1P + inp * 256 + l32 * 8 + j]);
        h2[j] = tanhf(ws[OFF_H2P + inp * 256 + l32 * 8 + j]);
    }
    f32x8 acc = {0.f, 0.f, 0.f, 0.f, 0.f, 0.f, 0.f, 0.f};
    int wid = bl * 4 + w;
    int base = wid * 2;
    for (; base + 1 < N; base += 8192) {
        int row = base + half;
        f32x8 v = x[(size_t)row * 32 + l32];
        float d = dot8(v, h1), e = dot8(v, h2);
#pragma unroll
        for (int off = 16; off; off >>= 1) {
            d += __shfl_xor(d, off, 64); e += __shfl_xor(e, off, 64);
        }
        float a1 = sigmoidf_(d);
        acc += (a1 * sigmoidf_(a1 * e)) * v;
    }
    if (base < N && half == 0) {
        f32x8 v = x[(size_t)base * 32 + l32];
        float d = dot8(v, h1), e = dot8(v, h2);
#pragma unroll
        for (int off = 16; off; off >>= 1) {
            d += __shfl_xor(d, off, 64); e += __shfl_xor(e, off, 64);
        }
        float a1 = sigmoidf_(d);
        acc += (a1 * sigmoidf_(a1 * e)) * v;
    }
    block_reduce_atomic8(acc, t, ws + OFF_OREP + inp * (REPS * 256) + (bl & (REPS - 1)) * 256);
}

// w_term[f] = g1.W[f].g2 with g=[o,o] folded; o recombined from OREP in-block.
__global__ void __launch_bounds__(256, 4)
k_ntn(const float* __restrict__ W, float* __restrict__ ws) {
    __shared__ __align__(16) float o_l[512];
    int b = blockIdx.x, t = threadIdx.x;
    {
        float s0 = 0.f, s1 = 0.f;
#pragma unroll
        for (int r2 = 0; r2 < REPS; r2++) {
            s0 += ws[OFF_OREP + r2 * 256 + t];
            s1 += ws[OFF_OREP + REPS * 256 + r2 * 256 + t];
        }
        o_l[t] = s0; o_l[256 + t] = s1;
    }
    __syncthreads();
    int lane = t & 63, w = t >> 6;
    f32x4 o2f = ((const f32x4*)(o_l + 256))[lane];
    int g = b * 4 + w;              // global wave id, 2048 waves
    const f32x4* W4 = (const f32x4*)W;
    float wt[4];
    int fidx[4];
#pragma unroll
    for (int u = 0; u < 4; u++) {
        int row = g + u * 2048;     // (f,d) flat, 8192 rows
        const f32x4* q = W4 + (size_t)row * 128 + lane;
        f32x4 m = (q[0] + q[64]) * o2f;
        float p = (m.x + m.y) + (m.z + m.w);
#pragma unroll
        for (int off = 32; off; off >>= 1) p += __shfl_xor(p, off, 64);
        wt[u] = o_l[row & 255] * p;
        fidx[u] = row >> 9;
    }
    if (lane == 0) {
        float* dst = ws + OFF_WTREP + (b & (REPS - 1)) * 16;
#pragma unroll
        for (int u = 0; u < 4; u++) atomicAdd(dst + fidx[u], wt[u]);
    }
}

// v_term + w_term + b -> sigmoid -> 4-layer MLP -> out[0]. o recombined in-block.
__global__ void k_final(const float* __restrict__ V, const float* __restrict__ bb,
                        const float* __restrict__ P0, const float* __restrict__ P1,
                        const float* __restrict__ P2, const float* __restrict__ P3,
                        float* __restrict__ ws, float* __restrict__ out) {
    int t = threadIdx.x;           // 256 threads
    __shared__ float o_l[512];
    {
        float s0 = 0.f, s1 = 0.f;
#pragma unroll
        for (int r2 = 0; r2 < REPS; r2++) {
            s0 += ws[OFF_OREP + r2 * 256 + t];
            s1 += ws[OFF_OREP + REPS * 256 + r2 * 256 + t];
        }
        o_l[t] = s0; o_l[256 + t] = s1;
    }
    __syncthreads();
    int f = t >> 4, j = t & 15;
    float p = 0.f;
    for (int k = j; k < 1024; k += 16) {
        float cv = (k < 512) ? o_l[k & 255] : o_l[256 + (k & 255)];
        p += cv * V[f * 1024 + k];
    }
    __shared__ float red[256];
    __shared__ float sv[16];
    red[t] = p;
    __syncthreads();
    if (t < 16) {
        float v = 0.f;
#pragma unroll
        for (int q = 0; q < 16; q++) v += red[t * 16 + q];
        float wt = 0.f;
#pragma unroll
        for (int r = 0; r < REPS; r++) wt += ws[OFF_WTREP + r * 16 + t];
        sv[t] = sigmoidf_(v + wt + bb[t]);
    }
    __syncthreads();
    if (t == 0) {
        float y0[8], y1[4], y2[2];
#pragma unroll
        for (int i = 0; i < 8; i++) {
            float s = 0.f;
            for (int k = 0; k < 16; k++) s += P0[i * 16 + k] * sv[k];
            y0[i] = sigmoidf_(s);
        }
#pragma unroll
        for (int i = 0; i < 4; i++) {
            float s = 0.f;
            for (int k = 0; k < 8; k++) s += P1[i * 8 + k] * y0[k];
            y1[i] = sigmoidf_(s);
        }
#pragma unroll
        for (int i = 0; i < 2; i++) {
            float s = 0.f;
            for (int k = 0; k < 4; k++) s += P2[i * 4 + k] * y1[k];
            y2[i] = sigmoidf_(s);
        }
        out[0] = sigmoidf_(P3[0] * y2[0] + P3[1] * y2[1]);
    }
}

extern "C" void kernel_launch(void* const* d_in, const int* in_sizes, int n_in,
                              void* d_out, int out_size, void* d_ws, size_t ws_size,
                              hipStream_t stream) {
    const float* x1 = (const float*)d_in[0];
    const float* x2 = (const float*)d_in[1];
    const float* W0 = (const float*)d_in[2];
    const float* V  = (const float*)d_in[3];
    const float* W  = (const float*)d_in[4];
    const float* b  = (const float*)d_in[5];
    const float* P0 = (const float*)d_in[6];
    const float* P1 = (const float*)d_in[7];
    const float* P2 = (const float*)d_in[8];
    const float* P3 = (const float*)d_in[9];
    float* ws  = (float*)d_ws;
    float* out = (float*)d_out;
    int N1 = in_sizes[0] / DD;   // 120000
    int N2 = in_sizes[1] / DD;   // 100000

    k_zero  <<<55,   256, 0, stream>>>(ws);
    k_colsum<<<1024, 256, 0, stream>>>((const f32x4*)x1, N1, 0, ws);
    k_colsum<<<1024, 256, 0, stream>>>((const f32x4*)x2, N2, 1, ws);
    k_hpart <<<32,   256, 0, stream>>>(W0, ws, OFF_SUMREP, OFF_H1P, N1, N2);
    k_att1  <<<2048, 256, 0, stream>>>((const f32x8*)x1, (const f32x8*)x2, N1, N2, ws);
    k_hpart <<<32,   256, 0, stream>>>(W0, ws, OFF_S1REP, OFF_H2P, N1, N2);
    k_att2  <<<2048, 256, 0, stream>>>((const f32x8*)x1, (const f32x8*)x2, N1, N2, ws);
    k_ntn   <<<512,  256, 0, stream>>>(W, ws);
    k_final <<<1,    256, 0, stream>>>(V, b, P0, P1, P2, P3, ws, out);
}

// Round 4
// 381.022 us; speedup vs baseline: 1.1547x; 1.1547x over previous
//
#include <hip/hip_runtime.h>
#include <math.h>

// Problem constants (from reference): D=256, DIN=512, F=16
#define DD 256
#define REPS 8   // replicated accumulators to reduce atomic same-address contention

// Workspace layout (float offsets) for the small stats region
#define OFF_SUMREP 0        // 2 inputs * REPS * 256 = 4096
#define OFF_H1P    4096     // 2 * 256 = 512   (pre-tanh partial sums, atomic target)
#define OFF_S1REP  4608     // 4096
#define OFF_H2P    8704     // 512
#define OFF_OREP   9216     // 4096
#define OFF_WTREP  13824    // REPS * 16 = 128
#define WS_FLOATS  13952
#define MIRROR_OFF_BYTES 65536   // fp16 mirror of x1,x2 starts here

typedef float    f32x4 __attribute__((ext_vector_type(4)));
typedef float    f32x8 __attribute__((ext_vector_type(8)));
typedef _Float16 f16x4 __attribute__((ext_vector_type(4)));
typedef _Float16 f16x8 __attribute__((ext_vector_type(8)));

__device__ __forceinline__ float sigmoidf_(float x) { return 1.0f / (1.0f + __expf(-x)); }

// row-of-8 loaders: fp16 mirror (convert) or raw fp32 (fallback)
__device__ __forceinline__ f32x8 ld8(const f16x8* p, size_t i) {
    return __builtin_convertvector(p[i], f32x8);
}
__device__ __forceinline__ f32x8 ld8(const f32x8* p, size_t i) { return p[i]; }

__device__ __forceinline__ float dot8(f32x8 a, f32x8 b) {
    f32x8 m = a * b;
    return ((m[0] + m[4]) + (m[1] + m[5])) + ((m[2] + m[6]) + (m[3] + m[7]));
}

__global__ void k_zero(float* __restrict__ ws) {
    int i = blockIdx.x * 256 + threadIdx.x;
    if (i < WS_FLOATS) ws[i] = 0.0f;
}

// f32x4 block reduce (4 waves) + replicated atomic finish (for k_mean).
__device__ __forceinline__ void block_reduce_atomic4(f32x4 acc, int t, float* dst_base) {
    __shared__ f32x4 lds[256];
    lds[t] = acc;
    __syncthreads();
    if (t < 64) {
        f32x4 s = lds[t] + lds[t + 64] + lds[t + 128] + lds[t + 192];
        float* dst = dst_base + t * 4;
        atomicAdd(dst + 0, s.x); atomicAdd(dst + 1, s.y);
        atomicAdd(dst + 2, s.z); atomicAdd(dst + 3, s.w);
    }
}

// f32x8 block reduce (8 half-wave slots) + replicated atomic finish (att kernels).
__device__ __forceinline__ void block_reduce_atomic8(f32x8 acc, int t, float* dst_base) {
    __shared__ f32x8 lds8[256];
    lds8[t] = acc;
    __syncthreads();
    const float* lf = (const float*)lds8;
    float s = 0.f;
#pragma unroll
    for (int slot = 0; slot < 8; slot++) s += lf[slot * 256 + t];   // conflict-free
    atomicAdd(dst_base + t, s);
}

// Pass A (R0 geometry, single experimental change: NON-TEMPORAL x loads).
// x is read exactly once per iteration; NT keeps it from allocating in L3 so
// the fp16 mirror (written here, read twice by att passes) stays L3-resident.
// Grid 1024: [0,512)->x1, [512,1024)->x2; wave-per-row, stride 2048 rows.
template<bool WM>
__global__ void k_mean_t(const f32x4* __restrict__ x1, const f32x4* __restrict__ x2,
                         f16x4* __restrict__ m1, f16x4* __restrict__ m2,
                         int N1, int N2, float* __restrict__ ws) {
    int b = blockIdx.x, t = threadIdx.x;
    int inp = (b < 512) ? 0 : 1;
    int bl = inp ? (b - 512) : b;
    const f32x4* x = inp ? x2 : x1;
    f16x4* mm = inp ? m2 : m1;
    int N = inp ? N2 : N1;
    int col4 = t & 63, rg = t >> 6;
    f32x4 acc = {0.f, 0.f, 0.f, 0.f};
    for (int r = bl * 4 + rg; r < N; r += 2048) {
        size_t i0 = (size_t)r * 64 + col4;
        f32x4 v = __builtin_nontemporal_load(&x[i0]);   // NT: don't evict mirror
        if (WM) mm[i0] = __builtin_convertvector(v, f16x4);
        acc += v;
    }
    block_reduce_atomic4(acc, t, ws + OFF_SUMREP + inp * (REPS * 256) + (bl & (REPS - 1)) * 256);
}

// hP[inp] += partial of (colsum/N) @ W0 over a 16-row slice of W0.
__global__ void k_hpart(const float* __restrict__ W0, float* __restrict__ ws,
                        int srcOff, int dstOff, int N1, int N2) {
    int inp = blockIdx.x >> 4, g = blockIdx.x & 15;
    int t = threadIdx.x;
    __shared__ float temp[16];
    if (t < 16) {
        const float* src = ws + srcOff + inp * (REPS * 256) + g * 16 + t;
        float s = 0.f;
#pragma unroll
        for (int r = 0; r < REPS; r++) s += src[r * 256];
        temp[t] = s * (1.0f / (float)(inp ? N2 : N1));
    }
    __syncthreads();
    float p = 0.f;
#pragma unroll
    for (int j = 0; j < 16; j++) p += temp[j] * W0[(g * 16 + j) * 256 + t];
    atomicAdd(ws + dstOff + inp * 256 + t, p);
}

// Pass B: s1 = sum_i sigmoid(x_i . h1) * x_i.
// 2 rows per wave (row = 32 lanes x 8 elems); grid 1024 (512/input), stride 4096 rows.
template<typename T>
__global__ void k_att1_t(const T* __restrict__ b1, const T* __restrict__ b2,
                         int N1, int N2, float* __restrict__ ws) {
    int b = blockIdx.x, t = threadIdx.x;
    int inp = (b < 512) ? 0 : 1;
    int bl = inp ? (b - 512) : b;
    const T* x = inp ? b2 : b1;
    int N = inp ? N2 : N1;
    int lane = t & 63, w = t >> 6;
    int half = lane >> 5, l32 = lane & 31;
    f32x8 h1;
#pragma unroll
    for (int j = 0; j < 8; j++) h1[j] = tanhf(ws[OFF_H1P + inp * 256 + l32 * 8 + j]);
    f32x8 acc = {0.f, 0.f, 0.f, 0.f, 0.f, 0.f, 0.f, 0.f};
    int wid = bl * 4 + w;
    int base = wid * 2;
    for (; base + 1 < N; base += 4096) {
        int row = base + half;
        f32x8 v = ld8(x, (size_t)row * 32 + l32);
        float d = dot8(v, h1);
#pragma unroll
        for (int off = 16; off; off >>= 1) d += __shfl_xor(d, off, 64);  // within 32-lane half
        acc += sigmoidf_(d) * v;
    }
    if (base < N && half == 0) {           // odd-N tail (dead for even N)
        f32x8 v = ld8(x, (size_t)base * 32 + l32);
        float d = dot8(v, h1);
#pragma unroll
        for (int off = 16; off; off >>= 1) d += __shfl_xor(d, off, 64);
        acc += sigmoidf_(d) * v;
    }
    block_reduce_atomic8(acc, t, ws + OFF_S1REP + inp * (REPS * 256) + (bl & (REPS - 1)) * 256);
}

// Pass C: o = sum_i att1_i*att2_i*x_i, att2_i = sigmoid(att1_i * (x_i . h2)).
template<typename T>
__global__ void k_att2_t(const T* __restrict__ b1, const T* __restrict__ b2,
                         int N1, int N2, float* __restrict__ ws) {
    int b = blockIdx.x, t = threadIdx.x;
    int inp = (b < 512) ? 0 : 1;
    int bl = inp ? (b - 512) : b;
    const T* x = inp ? b2 : b1;
    int N = inp ? N2 : N1;
    int lane = t & 63, w = t >> 6;
    int half = lane >> 5, l32 = lane & 31;
    f32x8 h1, h2;
#pragma unroll
    for (int j = 0; j < 8; j++) {
        h1[j] = tanhf(ws[OFF_H1P + inp * 256 + l32 * 8 + j]);
        h2[j] = tanhf(ws[OFF_H2P + inp * 256 + l32 * 8 + j]);
    }
    f32x8 acc = {0.f, 0.f, 0.f, 0.f, 0.f, 0.f, 0.f, 0.f};
    int wid = bl * 4 + w;
    int base = wid * 2;
    for (; base + 1 < N; base += 4096) {
        int row = base + half;
        f32x8 v = ld8(x, (size_t)row * 32 + l32);
        float d = dot8(v, h1), e = dot8(v, h2);
#pragma unroll
        for (int off = 16; off; off >>= 1) {
            d += __shfl_xor(d, off, 64); e += __shfl_xor(e, off, 64);
        }
        float a1 = sigmoidf_(d);
        acc += (a1 * sigmoidf_(a1 * e)) * v;
    }
    if (base < N && half == 0) {
        f32x8 v = ld8(x, (size_t)base * 32 + l32);
        float d = dot8(v, h1), e = dot8(v, h2);
#pragma unroll
        for (int off = 16; off; off >>= 1) {
            d += __shfl_xor(d, off, 64); e += __shfl_xor(e, off, 64);
        }
        float a1 = sigmoidf_(d);
        acc += (a1 * sigmoidf_(a1 * e)) * v;
    }
    block_reduce_atomic8(acc, t, ws + OFF_OREP + inp * (REPS * 256) + (bl & (REPS - 1)) * 256);
}

// w_term[f] = g1.W[f].g2 with g=[o,o] folded; o recombined from OREP in-block.
__global__ void __launch_bounds__(256, 4)
k_ntn(const float* __restrict__ W, float* __restrict__ ws) {
    __shared__ __align__(16) float o_l[512];
    int b = blockIdx.x, t = threadIdx.x;
    {
        float s0 = 0.f, s1 = 0.f;
#pragma unroll
        for (int r2 = 0; r2 < REPS; r2++) {
            s0 += ws[OFF_OREP + r2 * 256 + t];
            s1 += ws[OFF_OREP + REPS * 256 + r2 * 256 + t];
        }
        o_l[t] = s0; o_l[256 + t] = s1;
    }
    __syncthreads();
    int lane = t & 63, w = t >> 6;
    f32x4 o2f = ((const f32x4*)(o_l + 256))[lane];
    int g = b * 4 + w;              // global wave id, 2048 waves
    const f32x4* W4 = (const f32x4*)W;
    float wt[4];
    int fidx[4];
#pragma unroll
    for (int u = 0; u < 4; u++) {
        int row = g + u * 2048;     // (f,d) flat, 8192 rows
        const f32x4* q = W4 + (size_t)row * 128 + lane;
        f32x4 m = (q[0] + q[64]) * o2f;
        float p = (m.x + m.y) + (m.z + m.w);
#pragma unroll
        for (int off = 32; off; off >>= 1) p += __shfl_xor(p, off, 64);
        wt[u] = o_l[row & 255] * p;
        fidx[u] = row >> 9;
    }
    if (lane == 0) {
        float* dst = ws + OFF_WTREP + (b & (REPS - 1)) * 16;
#pragma unroll
        for (int u = 0; u < 4; u++) atomicAdd(dst + fidx[u], wt[u]);
    }
}

// v_term + w_term + b -> sigmoid -> 4-layer MLP -> out[0]. o recombined in-block.
__global__ void k_final(const float* __restrict__ V, const float* __restrict__ bb,
                        const float* __restrict__ P0, const float* __restrict__ P1,
                        const float* __restrict__ P2, const float* __restrict__ P3,
                        float* __restrict__ ws, float* __restrict__ out) {
    int t = threadIdx.x;           // 256 threads
    __shared__ float o_l[512];
    {
        float s0 = 0.f, s1 = 0.f;
#pragma unroll
        for (int r2 = 0; r2 < REPS; r2++) {
            s0 += ws[OFF_OREP + r2 * 256 + t];
            s1 += ws[OFF_OREP + REPS * 256 + r2 * 256 + t];
        }
        o_l[t] = s0; o_l[256 + t] = s1;
    }
    __syncthreads();
    int f = t >> 4, j = t & 15;
    float p = 0.f;
    for (int k = j; k < 1024; k += 16) {
        float cv = (k < 512) ? o_l[k & 255] : o_l[256 + (k & 255)];
        p += cv * V[f * 1024 + k];
    }
    __shared__ float red[256];
    __shared__ float sv[16];
    red[t] = p;
    __syncthreads();
    if (t < 16) {
        float v = 0.f;
#pragma unroll
        for (int q = 0; q < 16; q++) v += red[t * 16 + q];
        float wt = 0.f;
#pragma unroll
        for (int r = 0; r < REPS; r++) wt += ws[OFF_WTREP + r * 16 + t];
        sv[t] = sigmoidf_(v + wt + bb[t]);
    }
    __syncthreads();
    if (t == 0) {
        float y0[8], y1[4], y2[2];
#pragma unroll
        for (int i = 0; i < 8; i++) {
            float s = 0.f;
            for (int k = 0; k < 16; k++) s += P0[i * 16 + k] * sv[k];
            y0[i] = sigmoidf_(s);
        }
#pragma unroll
        for (int i = 0; i < 4; i++) {
            float s = 0.f;
            for (int k = 0; k < 8; k++) s += P1[i * 8 + k] * y0[k];
            y1[i] = sigmoidf_(s);
        }
#pragma unroll
        for (int i = 0; i < 2; i++) {
            float s = 0.f;
            for (int k = 0; k < 4; k++) s += P2[i * 4 + k] * y1[k];
            y2[i] = sigmoidf_(s);
        }
        out[0] = sigmoidf_(P3[0] * y2[0] + P3[1] * y2[1]);
    }
}

extern "C" void kernel_launch(void* const* d_in, const int* in_sizes, int n_in,
                              void* d_out, int out_size, void* d_ws, size_t ws_size,
                              hipStream_t stream) {
    const float* x1 = (const float*)d_in[0];
    const float* x2 = (const float*)d_in[1];
    const float* W0 = (const float*)d_in[2];
    const float* V  = (const float*)d_in[3];
    const float* W  = (const float*)d_in[4];
    const float* b  = (const float*)d_in[5];
    const float* P0 = (const float*)d_in[6];
    const float* P1 = (const float*)d_in[7];
    const float* P2 = (const float*)d_in[8];
    const float* P3 = (const float*)d_in[9];
    float* ws  = (float*)d_ws;
    float* out = (float*)d_out;
    int N1 = in_sizes[0] / DD;   // 120000
    int N2 = in_sizes[1] / DD;   // 100000

    const f32x4* x1v = (const f32x4*)x1;
    const f32x4* x2v = (const f32x4*)x2;
    f16x4* m1 = (f16x4*)((char*)d_ws + MIRROR_OFF_BYTES);
    f16x4* m2 = m1 + (size_t)N1 * 64;
    size_t need = (size_t)MIRROR_OFF_BYTES + ((size_t)N1 + N2) * DD * sizeof(_Float16);
    bool use_mirror = ws_size >= need;

    k_zero <<<55, 256, 0, stream>>>(ws);
    if (use_mirror) {
        k_mean_t<true>  <<<1024, 256, 0, stream>>>(x1v, x2v, m1, m2, N1, N2, ws);
        k_hpart         <<<32,   256, 0, stream>>>(W0, ws, OFF_SUMREP, OFF_H1P, N1, N2);
        k_att1_t<f16x8> <<<1024, 256, 0, stream>>>((const f16x8*)m1, (const f16x8*)m2, N1, N2, ws);
        k_hpart         <<<32,   256, 0, stream>>>(W0, ws, OFF_S1REP, OFF_H2P, N1, N2);
        k_att2_t<f16x8> <<<1024, 256, 0, stream>>>((const f16x8*)m1, (const f16x8*)m2, N1, N2, ws);
    } else {
        k_mean_t<false> <<<1024, 256, 0, stream>>>(x1v, x2v, nullptr, nullptr, N1, N2, ws);
        k_hpart         <<<32,   256, 0, stream>>>(W0, ws, OFF_SUMREP, OFF_H1P, N1, N2);
        k_att1_t<f32x8> <<<1024, 256, 0, stream>>>((const f32x8*)x1, (const f32x8*)x2, N1, N2, ws);
        k_hpart         <<<32,   256, 0, stream>>>(W0, ws, OFF_S1REP, OFF_H2P, N1, N2);
        k_att2_t<f32x8> <<<1024, 256, 0, stream>>>((const f32x8*)x1, (const f32x8*)x2, N1, N2, ws);
    }
    k_ntn  <<<512, 256, 0, stream>>>(W, ws);
    k_final<<<1,   256, 0, stream>>>(V, b, P0, P1, P2, P3, ws, out);
}